// Round 3
// baseline (167.209 us; speedup 1.0000x reference)
//
#include <hip/hip_runtime.h>
#include <cstddef>

// ---------------------------------------------------------------------------
// MHA block: y = attn(x@Wqkv+b) @ Wo + bo   (B=16,T=512,C=1024,H=16,hd=64)
// R3: m201-geometry GEMM (256x256, 8 waves, 4-phase/K-tile, counted vmcnt).
// ---------------------------------------------------------------------------

#define B_  16
#define T_  512
#define C_  1024
#define H_  16
#define HD_ 64

typedef __bf16 bf16x8 __attribute__((ext_vector_type(8)));
typedef float  f32x4  __attribute__((ext_vector_type(4)));

__device__ __forceinline__ void gload16(const void* g, void* lds_dst) {
  __builtin_amdgcn_global_load_lds(
      (const __attribute__((address_space(1))) unsigned int*)g,
      (__attribute__((address_space(3))) unsigned int*)lds_dst, 16, 0, 0);
}

// ------------------------- convert x: fp32 -> bf16 --------------------------
__global__ void cvt_kernel(const float* __restrict__ in, __bf16* __restrict__ out, int n) {
  int i = (blockIdx.x * 256 + threadIdx.x) * 8;
  if (i >= n) return;
  float4 f0 = *(const float4*)&in[i];
  float4 f1 = *(const float4*)&in[i + 4];
  bf16x8 o;
  o[0] = (__bf16)f0.x; o[1] = (__bf16)f0.y; o[2] = (__bf16)f0.z; o[3] = (__bf16)f0.w;
  o[4] = (__bf16)f1.x; o[5] = (__bf16)f1.y; o[6] = (__bf16)f1.z; o[7] = (__bf16)f1.w;
  *(bf16x8*)&out[i] = o;
}

// -------------- transpose+convert: w[K][N] fp32 -> wt[N][K] bf16 ------------
__global__ void tconv_kernel(const float* __restrict__ w, __bf16* __restrict__ wt,
                             int K, int N) {
  __shared__ float tile[32][33];
  int tx = threadIdx.x, ty = threadIdx.y;          // block (32,8)
  int n0 = blockIdx.x * 32, k0 = blockIdx.y * 32;
  #pragma unroll
  for (int i = 0; i < 4; ++i) {
    int r = ty + i * 8;
    tile[r][tx] = w[(size_t)(k0 + r) * N + n0 + tx];
  }
  __syncthreads();
  #pragma unroll
  for (int i = 0; i < 4; ++i) {
    int r = ty + i * 8;
    wt[(size_t)(n0 + r) * K + k0 + tx] = (__bf16)tile[tx][r];
  }
}

// ---------------------------------------------------------------------------
// GEMM: C[M][N] = A[M][K] @ BT[N][K]^T + bias[N]   (m201 geometry)
// Tile 256x256, BK=64, 8 waves (2M x 4N), per-wave 128x64 (8x4 16x16 frags).
// LDS 128KB: A dbuf 2x32KB @0, B dbuf 2x32KB @64KB. XOR swizzle (row&7)<<4,
// applied on the pre-swizzled GLOBAL source so global_load_lds dest is linear.
// Per K-tile t (buf p=t&1), 4 phases:
//   ph0: vmcnt(4)+barrier; read a0(8)+b0(4); stage B(t+1)->~p; 16 MFMA (0,0); bar
//   ph1: read b1(4);                          16 MFMA (0,1); bar
//   ph2: read a1(8);                          16 MFMA (1,0); bar
//   ph3: stage A(t+2)->p;                     16 MFMA (1,1); bar
// Stage(t) = A:4 issues in (t-2).ph3, B:4 issues in (t-1).ph0. vmcnt counts:
// entering ph0(t) outstanding = [t+1's A (4, newest)] + t's B -> vmcnt(4).
// ---------------------------------------------------------------------------
template<int EPI>
__global__ __launch_bounds__(512, 2) void gemm256_kernel(
    const __bf16* __restrict__ A, const __bf16* __restrict__ BT,
    const float* __restrict__ bias, int K, int NBn, int N,
    __bf16* __restrict__ oq, __bf16* __restrict__ okk, __bf16* __restrict__ ov,
    float* __restrict__ out32)
{
  extern __shared__ __align__(16) char lds[];
  const int tid = threadIdx.x, lane = tid & 63, wid = tid >> 6;
  const int wm = wid >> 2, wn = wid & 3;          // 2M x 4N
  const int lr = lane & 15, lg = lane >> 4;

  // bijective XCD swizzle (gridDim.x % 8 == 0)
  const int cpx = gridDim.x >> 3;
  const int id = (blockIdx.x & 7) * cpx + (blockIdx.x >> 3);
  const int m0 = (id / NBn) * 256, n0 = (id % NBn) * 256;

  // staging constants: one issue = 512 lanes x 16B = 8KB = 64 rows of 128B
  const int r8  = wid * 8 + (lane >> 3);
  const int csw = ((lane & 7) ^ (lane >> 3)) * 8;     // pre-swizzled col (elems)

  auto stage = [&](const __bf16* g, char* dst) {      // one 256x64 tile (4 issues)
    #pragma unroll
    for (int i = 0; i < 4; ++i)
      gload16(g + (size_t)(i * 64 + r8) * K + csw, dst + i * 8192 + wid * 1024);
  };

  auto rdA = [&](bf16x8* d, const char* Ab, int mh) { // 8 x ds_read_b128
    #pragma unroll
    for (int mf = 0; mf < 4; ++mf) {
      const char* rp = Ab + (wm * 128 + (mh * 4 + mf) * 16 + lr) * 128;
      #pragma unroll
      for (int ks = 0; ks < 2; ++ks)
        d[mf * 2 + ks] = *(const bf16x8*)(rp + (((ks << 2) + lg) ^ (lr & 7)) * 16);
    }
  };
  auto rdB = [&](bf16x8* d, const char* Bb, int nh) { // 4 x ds_read_b128
    #pragma unroll
    for (int nf = 0; nf < 2; ++nf) {
      const char* rp = Bb + (wn * 64 + (nh * 2 + nf) * 16 + lr) * 128;
      #pragma unroll
      for (int ks = 0; ks < 2; ++ks)
        d[nf * 2 + ks] = *(const bf16x8*)(rp + (((ks << 2) + lg) ^ (lr & 7)) * 16);
    }
  };

  f32x4 acc[8][4] = {};

  auto mm = [&](int mh, int nh, const bf16x8* av, const bf16x8* bv) {
    __builtin_amdgcn_s_setprio(1);
    #pragma unroll
    for (int mf = 0; mf < 4; ++mf)
      #pragma unroll
      for (int nf = 0; nf < 2; ++nf)
        #pragma unroll
        for (int ks = 0; ks < 2; ++ks)
          acc[mh * 4 + mf][nh * 2 + nf] = __builtin_amdgcn_mfma_f32_16x16x32_bf16(
              av[mf * 2 + ks], bv[nf * 2 + ks], acc[mh * 4 + mf][nh * 2 + nf], 0, 0, 0);
    __builtin_amdgcn_s_setprio(0);
  };

  const int nt = K >> 6;                              // 16
  const __bf16* gA = A  + (size_t)m0 * K;
  const __bf16* gB = BT + (size_t)n0 * K;

  // prologue: A(t0), B(t0), A(t1)   [12 issues; order matters for vmcnt]
  stage(gA, lds);
  stage(gB, lds + 65536);
  stage(gA + 64, lds + 32768);

  bf16x8 a0[8], a1[8], b0[4], b1[4];

  for (int t = 0; t < nt; ++t) {
    const int p = t & 1;
    char* Ab = lds + p * 32768;
    char* Bb = lds + 65536 + p * 32768;
    char* Bn = lds + 65536 + (p ^ 1) * 32768;

    // ---- ph0 ----
    if (t + 1 < nt) { asm volatile("s_waitcnt vmcnt(4)\ns_barrier" ::: "memory"); }
    else            { asm volatile("s_waitcnt vmcnt(0)\ns_barrier" ::: "memory"); }
    rdA(a0, Ab, 0);
    rdB(b0, Bb, 0);
    if (t + 1 < nt) stage(gB + (size_t)(t + 1) * 64, Bn);
    mm(0, 0, a0, b0);
    asm volatile("s_barrier" ::: "memory");

    // ---- ph1 ----
    rdB(b1, Bb, 1);
    mm(0, 1, a0, b1);
    asm volatile("s_barrier" ::: "memory");

    // ---- ph2 ----
    rdA(a1, Ab, 1);
    mm(1, 0, a1, b0);
    asm volatile("s_barrier" ::: "memory");

    // ---- ph3 ----
    if (t + 2 < nt) stage(gA + (size_t)(t + 2) * 64, Ab);
    mm(1, 1, a1, b1);
    asm volatile("s_barrier" ::: "memory");
  }

  // ---- epilogue ----
  #pragma unroll
  for (int nf = 0; nf < 4; ++nf) {
    int n = n0 + wn * 64 + nf * 16 + lr;
    float bv = bias[n];
    if (EPI == 0) {
      int which = n >> 10;
      __bf16* dst = (which == 0) ? oq : (which == 1) ? okk : ov;
      int h = (n >> 6) & 15, d = n & 63;
      #pragma unroll
      for (int mf = 0; mf < 8; ++mf)
        #pragma unroll
        for (int j = 0; j < 4; ++j) {
          int m = m0 + wm * 128 + mf * 16 + lg * 4 + j;
          int bb = m >> 9, tt = m & 511;
          dst[(size_t)((bb * H_ + h) * T_ + tt) * HD_ + d] =
              (__bf16)(acc[mf][nf][j] + bv);
        }
    } else {
      #pragma unroll
      for (int mf = 0; mf < 8; ++mf)
        #pragma unroll
        for (int j = 0; j < 4; ++j) {
          int m = m0 + wm * 128 + mf * 16 + lg * 4 + j;
          out32[(size_t)m * N + n] = acc[mf][nf][j] + bv;
        }
    }
  }
}

// ---------------------------------------------------------------------------
// Flash attention (causal). Grid (B*H, T/64). 4 waves, each wave 16 q-rows.
// R3: T14 prefetch — next chunk's K/V loaded into regs under current compute.
// ---------------------------------------------------------------------------
__global__ __launch_bounds__(256, 2) void attn_kernel(
    const __bf16* __restrict__ qb, const __bf16* __restrict__ kb,
    const __bf16* __restrict__ vb, __bf16* __restrict__ y)
{
  __shared__ __attribute__((aligned(16))) __bf16 Ks[64][72];
  __shared__ __attribute__((aligned(16))) __bf16 Vt[64][72];
  __shared__ __attribute__((aligned(16))) __bf16 Ps[4][16][72];

  const int tid = threadIdx.x, lane = tid & 63, w = tid >> 6;
  const int lr = lane & 15, lg = lane >> 4;
  const int bh = blockIdx.x, qt = blockIdx.y;
  const size_t base = (size_t)bh * T_ * HD_;
  const int q0 = qt * 64 + w * 16;
  const float SCALE = 0.03125f;                   // 1/sqrt(1024)
  const float L2E = 1.44269504088896f;

  bf16x8 qf[2];
  #pragma unroll
  for (int s = 0; s < 2; ++s)
    qf[s] = *(const bf16x8*)&qb[base + (size_t)(q0 + lr) * HD_ + s * 32 + lg * 8];

  f32x4 acc[4] = {};
  float mrun[4] = { -__builtin_inff(), -__builtin_inff(),
                    -__builtin_inff(), -__builtin_inff() };
  float lrun[4] = { 0.f, 0.f, 0.f, 0.f };

  bf16x8 kk[2], vv[2], kk2[2], vv2[2];
  #pragma unroll
  for (int p = 0; p < 2; ++p) {
    int t8 = p * 256 + tid;
    kk[p] = *(const bf16x8*)&kb[base + t8 * 8];
    vv[p] = *(const bf16x8*)&vb[base + t8 * 8];
  }

  for (int c = 0; c <= qt; ++c) {
    // ---- write staged regs: K row-major (padded), V transposed ----
    #pragma unroll
    for (int p = 0; p < 2; ++p) {
      int t8 = p * 256 + tid;
      int r = t8 >> 3, col = (t8 & 7) * 8;
      *(bf16x8*)&Ks[r][col] = kk[p];
      #pragma unroll
      for (int i = 0; i < 8; ++i) Vt[col + i][r] = vv[p][i];
    }
    __syncthreads();

    // ---- prefetch next chunk under compute ----
    if (c < qt) {
      #pragma unroll
      for (int p = 0; p < 2; ++p) {
        int t8 = p * 256 + tid;
        kk2[p] = *(const bf16x8*)&kb[base + (size_t)(c + 1) * 4096 + t8 * 8];
        vv2[p] = *(const bf16x8*)&vb[base + (size_t)(c + 1) * 4096 + t8 * 8];
      }
    }

    // ---- S = Q K^T (16 q x 64 kv) ----
    f32x4 sc[4] = {};
    #pragma unroll
    for (int s = 0; s < 2; ++s) {
      #pragma unroll
      for (int cc = 0; cc < 4; ++cc) {
        bf16x8 kf = *(const bf16x8*)&Ks[cc * 16 + lr][s * 32 + lg * 8];
        sc[cc] = __builtin_amdgcn_mfma_f32_16x16x32_bf16(qf[s], kf, sc[cc], 0, 0, 0);
      }
    }

    // ---- scale + causal mask ----
    #pragma unroll
    for (int cc = 0; cc < 4; ++cc)
      #pragma unroll
      for (int j = 0; j < 4; ++j) {
        float v = sc[cc][j] * SCALE;
        if (c == qt) {
          int kv = c * 64 + cc * 16 + lr;
          int qr = q0 + lg * 4 + j;
          if (kv > qr) v = -__builtin_inff();
        }
        sc[cc][j] = v;
      }

    // ---- online softmax ----
    float mx[4];
    #pragma unroll
    for (int j = 0; j < 4; ++j)
      mx[j] = fmaxf(fmaxf(sc[0][j], sc[1][j]), fmaxf(sc[2][j], sc[3][j]));
    #pragma unroll
    for (int msk = 1; msk <= 8; msk <<= 1)
      #pragma unroll
      for (int j = 0; j < 4; ++j)
        mx[j] = fmaxf(mx[j], __shfl_xor(mx[j], msk, 64));
    float corr[4];
    #pragma unroll
    for (int j = 0; j < 4; ++j) {
      float nm = fmaxf(mrun[j], mx[j]);
      corr[j] = exp2f((mrun[j] - nm) * L2E);
      mrun[j] = nm;
    }
    #pragma unroll
    for (int cc = 0; cc < 4; ++cc)
      #pragma unroll
      for (int j = 0; j < 4; ++j)
        sc[cc][j] = exp2f((sc[cc][j] - mrun[j]) * L2E);
    float rs[4];
    #pragma unroll
    for (int j = 0; j < 4; ++j)
      rs[j] = sc[0][j] + sc[1][j] + sc[2][j] + sc[3][j];
    #pragma unroll
    for (int msk = 1; msk <= 8; msk <<= 1)
      #pragma unroll
      for (int j = 0; j < 4; ++j)
        rs[j] += __shfl_xor(rs[j], msk, 64);
    #pragma unroll
    for (int j = 0; j < 4; ++j)
      lrun[j] = lrun[j] * corr[j] + rs[j];
    #pragma unroll
    for (int dd = 0; dd < 4; ++dd)
      #pragma unroll
      for (int j = 0; j < 4; ++j)
        acc[dd][j] *= corr[j];

    // ---- P: C-layout -> A-layout via per-wave LDS ----
    #pragma unroll
    for (int cc = 0; cc < 4; ++cc)
      #pragma unroll
      for (int j = 0; j < 4; ++j)
        Ps[w][lg * 4 + j][cc * 16 + lr] = (__bf16)sc[cc][j];

    // ---- O += P V ----
    #pragma unroll
    for (int s = 0; s < 2; ++s) {
      bf16x8 pa = *(const bf16x8*)&Ps[w][lr][s * 32 + lg * 8];
      #pragma unroll
      for (int dd = 0; dd < 4; ++dd) {
        bf16x8 vf = *(const bf16x8*)&Vt[dd * 16 + lr][s * 32 + lg * 8];
        acc[dd] = __builtin_amdgcn_mfma_f32_16x16x32_bf16(pa, vf, acc[dd], 0, 0, 0);
      }
    }
    __syncthreads();
    #pragma unroll
    for (int p = 0; p < 2; ++p) { kk[p] = kk2[p]; vv[p] = vv2[p]; }
  }

  const int b = bh >> 4, h = bh & 15;
  #pragma unroll
  for (int dd = 0; dd < 4; ++dd)
    #pragma unroll
    for (int j = 0; j < 4; ++j) {
      int t = q0 + lg * 4 + j;
      int d = dd * 16 + lr;
      y[((size_t)(b * T_ + t)) * C_ + h * HD_ + d] = (__bf16)(acc[dd][j] / lrun[j]);
    }
}

// ---------------------------------------------------------------------------
extern "C" void kernel_launch(void* const* d_in, const int* in_sizes, int n_in,
                              void* d_out, int out_size, void* d_ws, size_t ws_size,
                              hipStream_t stream) {
  const float* x    = (const float*)d_in[0];
  const float* wqkv = (const float*)d_in[1];
  const float* bqkv = (const float*)d_in[2];
  const float* wo   = (const float*)d_in[3];
  const float* bo   = (const float*)d_in[4];
  float* out = (float*)d_out;

  char* ws = (char*)d_ws;
  const size_t MB = 1u << 20;
  __bf16* xb   = (__bf16*)(ws);              // 16 MB  x bf16 [8192][1024]
  __bf16* wqt  = (__bf16*)(ws + 16 * MB);    //  6 MB  w_qkv^T bf16 [3072][1024]
  __bf16* wot  = (__bf16*)(ws + 22 * MB);    //  2 MB  w_o^T bf16 [1024][1024]
  __bf16* qbuf = (__bf16*)(ws + 24 * MB);    // 16 MB  Q [B,H,T,HD]
  __bf16* kbuf = (__bf16*)(ws + 40 * MB);    // 16 MB  K
  __bf16* vbuf = (__bf16*)(ws + 56 * MB);    // 16 MB  V
  __bf16* ybuf = (__bf16*)(ws + 72 * MB);    // 16 MB  attn out [B,T,C]

  (void)hipFuncSetAttribute(reinterpret_cast<const void*>(&gemm256_kernel<0>),
                            hipFuncAttributeMaxDynamicSharedMemorySize, 131072);
  (void)hipFuncSetAttribute(reinterpret_cast<const void*>(&gemm256_kernel<1>),
                            hipFuncAttributeMaxDynamicSharedMemorySize, 131072);

  const int NX = B_ * T_ * C_;               // 8388608
  cvt_kernel<<<NX / (256 * 8), 256, 0, stream>>>(x, xb, NX);
  tconv_kernel<<<dim3(3 * C_ / 32, C_ / 32), dim3(32, 8), 0, stream>>>(wqkv, wqt, C_, 3 * C_);
  tconv_kernel<<<dim3(C_ / 32, C_ / 32), dim3(32, 8), 0, stream>>>(wo, wot, C_, C_);

  // QKV: M=8192, N=3072 -> 32 x 12 = 384 blocks
  gemm256_kernel<0><<<384, 512, 131072, stream>>>(
      xb, wqt, bqkv, C_, 12, 3 * C_, qbuf, kbuf, vbuf, nullptr);

  attn_kernel<<<dim3(B_ * H_, T_ / 64), 256, 0, stream>>>(qbuf, kbuf, vbuf, ybuf);

  // out-proj: M=8192, N=1024 -> 32 x 4 = 128 blocks
  gemm256_kernel<1><<<128, 512, 131072, stream>>>(
      ybuf, wot, bo, C_, 4, C_, nullptr, nullptr, nullptr, out);
}

// Round 4
// 155.626 us; speedup vs baseline: 1.0744x; 1.0744x over previous
//
#include <hip/hip_runtime.h>
#include <cstddef>

// ---------------------------------------------------------------------------
// MHA block: y = attn(x@Wqkv+b) @ Wo + bo   (B=16,T=512,C=1024,H=16,hd=64)
// R4: 128x256 GEMM tile (even rounds: 768/256 blocks), 2-phase K-loop,
// B triple-buffered (vmcnt(6) steady state), pre-transposed V for attention.
// ---------------------------------------------------------------------------

#define B_  16
#define T_  512
#define C_  1024
#define H_  16
#define HD_ 64

typedef __bf16 bf16x8 __attribute__((ext_vector_type(8)));
typedef float  f32x4  __attribute__((ext_vector_type(4)));

__device__ __forceinline__ void gload16(const void* g, void* lds_dst) {
  __builtin_amdgcn_global_load_lds(
      (const __attribute__((address_space(1))) unsigned int*)g,
      (__attribute__((address_space(3))) unsigned int*)lds_dst, 16, 0, 0);
}

// ------------------------- convert x: fp32 -> bf16 --------------------------
__global__ void cvt_kernel(const float* __restrict__ in, __bf16* __restrict__ out, int n) {
  int i = (blockIdx.x * 256 + threadIdx.x) * 8;
  if (i >= n) return;
  float4 f0 = *(const float4*)&in[i];
  float4 f1 = *(const float4*)&in[i + 4];
  bf16x8 o;
  o[0] = (__bf16)f0.x; o[1] = (__bf16)f0.y; o[2] = (__bf16)f0.z; o[3] = (__bf16)f0.w;
  o[4] = (__bf16)f1.x; o[5] = (__bf16)f1.y; o[6] = (__bf16)f1.z; o[7] = (__bf16)f1.w;
  *(bf16x8*)&out[i] = o;
}

// -------------- transpose+convert: w[K][N] fp32 -> wt[N][K] bf16 ------------
__global__ void tconv_kernel(const float* __restrict__ w, __bf16* __restrict__ wt,
                             int K, int N) {
  __shared__ float tile[32][33];
  int tx = threadIdx.x, ty = threadIdx.y;          // block (32,8)
  int n0 = blockIdx.x * 32, k0 = blockIdx.y * 32;
  #pragma unroll
  for (int i = 0; i < 4; ++i) {
    int r = ty + i * 8;
    tile[r][tx] = w[(size_t)(k0 + r) * N + n0 + tx];
  }
  __syncthreads();
  #pragma unroll
  for (int i = 0; i < 4; ++i) {
    int r = ty + i * 8;
    wt[(size_t)(n0 + r) * K + k0 + tx] = (__bf16)tile[tx][r];
  }
}

// ---------------- V transpose: v[bh][t][d] -> vt[bh][d][t] ------------------
__global__ void vtr_kernel(const __bf16* __restrict__ v, __bf16* __restrict__ vt) {
  __shared__ __bf16 tile[64][68];
  const int tid = threadIdx.x;
  const int bh = blockIdx.x, tc = blockIdx.y;      // 64-row t-chunk
  const size_t base = (size_t)bh * T_ * HD_;
  #pragma unroll
  for (int p = 0; p < 2; ++p) {
    int t8 = p * 256 + tid;
    int r = t8 >> 3, col = (t8 & 7) * 8;
    *(bf16x8*)&tile[r][col] =
        *(const bf16x8*)&v[base + (size_t)(tc * 64 + r) * HD_ + col];
  }
  __syncthreads();
  #pragma unroll
  for (int p = 0; p < 2; ++p) {
    int t8 = p * 256 + tid;
    int d = t8 >> 3, tt = (t8 & 7) * 8;
    bf16x8 o;
    #pragma unroll
    for (int i = 0; i < 8; ++i) o[i] = tile[tt + i][d];
    *(bf16x8*)&vt[base + (size_t)d * T_ + tc * 64 + tt] = o;
  }
}

// ---------------------------------------------------------------------------
// GEMM: C[M][N] = A[M][K] @ BT[N][K]^T + bias[N]
// Tile 128x256, BK=64, 8 waves (2M x 4N), per-wave 64x64 (4x4 16x16 frags).
// LDS 128KB: A dbuf 2x16KB @0, B tribuf 3x32KB @32KB. XOR swizzle on frag
// reads; staging pre-swizzles the GLOBAL source so gload_lds dest is linear.
// Per K-tile t (Abuf pA=t&1, Bbuf iB=t%3), 2 phases:
//   ph0: vmcnt(6)+bar; read a(8)+b0(4); stage B(t+2)->(t+2)%3; 16 MFMA nf01; bar
//   ph1: read b1(4);                    stage A(t+2)->pA;      16 MFMA nf23; bar
// Outstanding entering ph0(t) = B(t+1)[4] + A(t+1)[2] = 6 -> vmcnt(6).
// Hazards: A(t+2)->pA issued in ph1 after a-reads retired (ph0 MFMA lgkm);
// B(t+2) overwrites (t-1)%3 whose reads retired in tile t-1 (+2 barriers).
// ---------------------------------------------------------------------------
template<int EPI>
__global__ __launch_bounds__(512, 2) void gemm128_kernel(
    const __bf16* __restrict__ A, const __bf16* __restrict__ BT,
    const float* __restrict__ bias, int K, int NBn, int N,
    __bf16* __restrict__ oq, __bf16* __restrict__ okk, __bf16* __restrict__ ov,
    float* __restrict__ out32)
{
  extern __shared__ __align__(16) char lds[];
  const int tid = threadIdx.x, lane = tid & 63, wid = tid >> 6;
  const int wm = wid >> 2, wn = wid & 3;          // 2M x 4N
  const int lr = lane & 15, lg = lane >> 4;

  // bijective XCD swizzle (gridDim.x % 8 == 0)
  const int cpx = gridDim.x >> 3;
  const int id = (blockIdx.x & 7) * cpx + (blockIdx.x >> 3);
  const int m0 = (id / NBn) * 128, n0 = (id % NBn) * 256;

  // staging: one issue = 512 lanes x 16B = 8KB = 64 rows of 128B
  const int r8  = wid * 8 + (lane >> 3);
  const int csw = ((lane & 7) ^ (lane >> 3)) * 8;     // pre-swizzled col (elems)

  auto stageA = [&](const __bf16* g, char* dst) {     // 128x64 tile, 2 issues
    #pragma unroll
    for (int i = 0; i < 2; ++i)
      gload16(g + (size_t)(i * 64 + r8) * K + csw, dst + i * 8192 + wid * 1024);
  };
  auto stageB = [&](const __bf16* g, char* dst) {     // 256x64 tile, 4 issues
    #pragma unroll
    for (int i = 0; i < 4; ++i)
      gload16(g + (size_t)(i * 64 + r8) * K + csw, dst + i * 8192 + wid * 1024);
  };

  auto rdA = [&](bf16x8* d, const char* Ab) {         // 8 x ds_read_b128
    #pragma unroll
    for (int mf = 0; mf < 4; ++mf) {
      const char* rp = Ab + (wm * 64 + mf * 16 + lr) * 128;
      #pragma unroll
      for (int ks = 0; ks < 2; ++ks)
        d[mf * 2 + ks] = *(const bf16x8*)(rp + (((ks << 2) + lg) ^ (lr & 7)) * 16);
    }
  };
  auto rdB = [&](bf16x8* d, const char* Bb, int nh) { // 4 x ds_read_b128
    #pragma unroll
    for (int nfl = 0; nfl < 2; ++nfl) {
      const char* rp = Bb + (wn * 64 + (nh * 2 + nfl) * 16 + lr) * 128;
      #pragma unroll
      for (int ks = 0; ks < 2; ++ks)
        d[nfl * 2 + ks] = *(const bf16x8*)(rp + (((ks << 2) + lg) ^ (lr & 7)) * 16);
    }
  };

  f32x4 acc[4][4] = {};

  auto mm = [&](const bf16x8* av, const bf16x8* bv, int nh) {   // 16 MFMA
    __builtin_amdgcn_s_setprio(1);
    #pragma unroll
    for (int mf = 0; mf < 4; ++mf)
      #pragma unroll
      for (int nfl = 0; nfl < 2; ++nfl)
        #pragma unroll
        for (int ks = 0; ks < 2; ++ks)
          acc[mf][nh * 2 + nfl] = __builtin_amdgcn_mfma_f32_16x16x32_bf16(
              av[mf * 2 + ks], bv[nfl * 2 + ks], acc[mf][nh * 2 + nfl], 0, 0, 0);
    __builtin_amdgcn_s_setprio(0);
  };

  const int nt = K >> 6;                              // 16
  const __bf16* gA = A  + (size_t)m0 * K;
  const __bf16* gB = BT + (size_t)n0 * K;
  char* const Ab0 = lds;
  char* const Bb0 = lds + 32768;

  // prologue (order matters for vmcnt): B(0),A(0),B(1),A(1) -> 12 outstanding
  stageB(gB, Bb0);
  stageA(gA, Ab0);
  stageB(gB + 64, Bb0 + 32768);
  stageA(gA + 64, Ab0 + 16384);

  bf16x8 a[8], b0[4], b1[4];

  for (int t = 0; t < nt; ++t) {
    char* Ab = Ab0 + (t & 1) * 16384;
    char* Bb = Bb0 + (t % 3) * 32768;

    // ---- ph0 ----
    if (t + 1 < nt) { asm volatile("s_waitcnt vmcnt(6)\ns_barrier" ::: "memory"); }
    else            { asm volatile("s_waitcnt vmcnt(0)\ns_barrier" ::: "memory"); }
    rdA(a, Ab);
    rdB(b0, Bb, 0);
    if (t + 2 < nt) stageB(gB + (size_t)(t + 2) * 64, Bb0 + ((t + 2) % 3) * 32768);
    mm(a, b0, 0);
    asm volatile("s_barrier" ::: "memory");

    // ---- ph1 ----
    rdB(b1, Bb, 1);
    if (t + 2 < nt) stageA(gA + (size_t)(t + 2) * 64, Ab);
    mm(a, b1, 1);
    asm volatile("s_barrier" ::: "memory");
  }

  // ---- epilogue: D row = lg*4+j, col = lr within each 16x16 frag ----
  #pragma unroll
  for (int nf = 0; nf < 4; ++nf) {
    int n = n0 + wn * 64 + nf * 16 + lr;
    float bv = bias[n];
    if (EPI == 0) {
      int which = n >> 10;
      __bf16* dst = (which == 0) ? oq : (which == 1) ? okk : ov;
      int h = (n >> 6) & 15, d = n & 63;
      #pragma unroll
      for (int mf = 0; mf < 4; ++mf)
        #pragma unroll
        for (int j = 0; j < 4; ++j) {
          int m = m0 + wm * 64 + mf * 16 + lg * 4 + j;
          int bb = m >> 9, tt = m & 511;
          dst[(size_t)((bb * H_ + h) * T_ + tt) * HD_ + d] =
              (__bf16)(acc[mf][nf][j] + bv);
        }
    } else {
      #pragma unroll
      for (int mf = 0; mf < 4; ++mf)
        #pragma unroll
        for (int j = 0; j < 4; ++j) {
          int m = m0 + wm * 64 + mf * 16 + lg * 4 + j;
          out32[(size_t)m * N + n] = acc[mf][nf][j] + bv;
        }
    }
  }
}

// ---------------------------------------------------------------------------
// Flash attention (causal). Grid (B*H, T/64). 4 waves, each wave 16 q-rows.
// V pre-transposed: vt[bh][d][t] -> Vt staging is coalesced b128, no scatter.
// ---------------------------------------------------------------------------
__global__ __launch_bounds__(256, 2) void attn_kernel(
    const __bf16* __restrict__ qb, const __bf16* __restrict__ kb,
    const __bf16* __restrict__ vtb, __bf16* __restrict__ y)
{
  __shared__ __attribute__((aligned(16))) __bf16 Ks[64][72];
  __shared__ __attribute__((aligned(16))) __bf16 Vt[64][72];
  __shared__ __attribute__((aligned(16))) __bf16 Ps[4][16][72];

  const int tid = threadIdx.x, lane = tid & 63, w = tid >> 6;
  const int lr = lane & 15, lg = lane >> 4;
  const int bh = blockIdx.x, qt = blockIdx.y;
  const size_t base = (size_t)bh * T_ * HD_;
  const int q0 = qt * 64 + w * 16;
  const float SCALE = 0.03125f;                   // 1/sqrt(1024)
  const float L2E = 1.44269504088896f;

  const int r_  = tid >> 3;                       // 0..31 (+32 for p=1)
  const int c8_ = (tid & 7) * 8;

  bf16x8 qf[2];
  #pragma unroll
  for (int s = 0; s < 2; ++s)
    qf[s] = *(const bf16x8*)&qb[base + (size_t)(q0 + lr) * HD_ + s * 32 + lg * 8];

  f32x4 acc[4] = {};
  float mrun[4] = { -__builtin_inff(), -__builtin_inff(),
                    -__builtin_inff(), -__builtin_inff() };
  float lrun[4] = { 0.f, 0.f, 0.f, 0.f };

  bf16x8 kk[2], vv[2], kk2[2], vv2[2];
  #pragma unroll
  for (int p = 0; p < 2; ++p) {
    int rr = p * 32 + r_;
    kk[p] = *(const bf16x8*)&kb[base + (size_t)rr * HD_ + c8_];
    vv[p] = *(const bf16x8*)&vtb[base + (size_t)rr * T_ + c8_];
  }

  for (int c = 0; c <= qt; ++c) {
    // ---- write staged regs: K [kv][d], Vt [d][kv] — both b128 ----
    #pragma unroll
    for (int p = 0; p < 2; ++p) {
      int rr = p * 32 + r_;
      *(bf16x8*)&Ks[rr][c8_] = kk[p];
      *(bf16x8*)&Vt[rr][c8_] = vv[p];
    }
    __syncthreads();

    // ---- prefetch next chunk under compute ----
    if (c < qt) {
      #pragma unroll
      for (int p = 0; p < 2; ++p) {
        int rr = p * 32 + r_;
        kk2[p] = *(const bf16x8*)&kb[base + (size_t)(c + 1) * 64 * HD_ + (size_t)rr * HD_ + c8_];
        vv2[p] = *(const bf16x8*)&vtb[base + (size_t)rr * T_ + (c + 1) * 64 + c8_];
      }
    }

    // ---- S = Q K^T (16 q x 64 kv) ----
    f32x4 sc[4] = {};
    #pragma unroll
    for (int s = 0; s < 2; ++s) {
      #pragma unroll
      for (int cc = 0; cc < 4; ++cc) {
        bf16x8 kf = *(const bf16x8*)&Ks[cc * 16 + lr][s * 32 + lg * 8];
        sc[cc] = __builtin_amdgcn_mfma_f32_16x16x32_bf16(qf[s], kf, sc[cc], 0, 0, 0);
      }
    }

    // ---- scale + causal mask ----
    #pragma unroll
    for (int cc = 0; cc < 4; ++cc)
      #pragma unroll
      for (int j = 0; j < 4; ++j) {
        float v = sc[cc][j] * SCALE;
        if (c == qt) {
          int kv = c * 64 + cc * 16 + lr;
          int qr = q0 + lg * 4 + j;
          if (kv > qr) v = -__builtin_inff();
        }
        sc[cc][j] = v;
      }

    // ---- online softmax ----
    float mx[4];
    #pragma unroll
    for (int j = 0; j < 4; ++j)
      mx[j] = fmaxf(fmaxf(sc[0][j], sc[1][j]), fmaxf(sc[2][j], sc[3][j]));
    #pragma unroll
    for (int msk = 1; msk <= 8; msk <<= 1)
      #pragma unroll
      for (int j = 0; j < 4; ++j)
        mx[j] = fmaxf(mx[j], __shfl_xor(mx[j], msk, 64));
    float corr[4];
    #pragma unroll
    for (int j = 0; j < 4; ++j) {
      float nm = fmaxf(mrun[j], mx[j]);
      corr[j] = exp2f((mrun[j] - nm) * L2E);
      mrun[j] = nm;
    }
    #pragma unroll
    for (int cc = 0; cc < 4; ++cc)
      #pragma unroll
      for (int j = 0; j < 4; ++j)
        sc[cc][j] = exp2f((sc[cc][j] - mrun[j]) * L2E);
    float rs[4];
    #pragma unroll
    for (int j = 0; j < 4; ++j)
      rs[j] = sc[0][j] + sc[1][j] + sc[2][j] + sc[3][j];
    #pragma unroll
    for (int msk = 1; msk <= 8; msk <<= 1)
      #pragma unroll
      for (int j = 0; j < 4; ++j)
        rs[j] += __shfl_xor(rs[j], msk, 64);
    #pragma unroll
    for (int j = 0; j < 4; ++j)
      lrun[j] = lrun[j] * corr[j] + rs[j];
    #pragma unroll
    for (int dd = 0; dd < 4; ++dd)
      #pragma unroll
      for (int j = 0; j < 4; ++j)
        acc[dd][j] *= corr[j];

    // ---- P: C-layout -> A-layout via per-wave LDS ----
    #pragma unroll
    for (int cc = 0; cc < 4; ++cc)
      #pragma unroll
      for (int j = 0; j < 4; ++j)
        Ps[w][lg * 4 + j][cc * 16 + lr] = (__bf16)sc[cc][j];

    // ---- O += P V ----
    #pragma unroll
    for (int s = 0; s < 2; ++s) {
      bf16x8 pa = *(const bf16x8*)&Ps[w][lr][s * 32 + lg * 8];
      #pragma unroll
      for (int dd = 0; dd < 4; ++dd) {
        bf16x8 vf = *(const bf16x8*)&Vt[dd * 16 + lr][s * 32 + lg * 8];
        acc[dd] = __builtin_amdgcn_mfma_f32_16x16x32_bf16(pa, vf, acc[dd], 0, 0, 0);
      }
    }
    __syncthreads();
    #pragma unroll
    for (int p = 0; p < 2; ++p) { kk[p] = kk2[p]; vv[p] = vv2[p]; }
  }

  const int b = bh >> 4, h = bh & 15;
  #pragma unroll
  for (int dd = 0; dd < 4; ++dd)
    #pragma unroll
    for (int j = 0; j < 4; ++j) {
      int t = q0 + lg * 4 + j;
      int d = dd * 16 + lr;
      y[((size_t)(b * T_ + t)) * C_ + h * HD_ + d] = (__bf16)(acc[dd][j] / lrun[j]);
    }
}

// ---------------------------------------------------------------------------
extern "C" void kernel_launch(void* const* d_in, const int* in_sizes, int n_in,
                              void* d_out, int out_size, void* d_ws, size_t ws_size,
                              hipStream_t stream) {
  const float* x    = (const float*)d_in[0];
  const float* wqkv = (const float*)d_in[1];
  const float* bqkv = (const float*)d_in[2];
  const float* wo   = (const float*)d_in[3];
  const float* bo   = (const float*)d_in[4];
  float* out = (float*)d_out;

  char* ws = (char*)d_ws;
  const size_t MB = 1u << 20;
  __bf16* xb    = (__bf16*)(ws);              // 16 MB  x bf16 [8192][1024]
  __bf16* wqt   = (__bf16*)(ws + 16 * MB);    //  6 MB  w_qkv^T bf16 [3072][1024]
  __bf16* wot   = (__bf16*)(ws + 22 * MB);    //  2 MB  w_o^T bf16 [1024][1024]
  __bf16* qbuf  = (__bf16*)(ws + 24 * MB);    // 16 MB  Q [B,H,T,HD]
  __bf16* kbuf  = (__bf16*)(ws + 40 * MB);    // 16 MB  K [B,H,T,HD]
  __bf16* vbuf  = (__bf16*)(ws + 56 * MB);    // 16 MB  V [B,H,T,HD]
  __bf16* ybuf  = (__bf16*)(ws + 56 * MB);    // aliases vbuf (dead after vtr)
  __bf16* vtbuf = (__bf16*)(ws + 72 * MB);    // 16 MB  V^T [B,H,HD,T]

  (void)hipFuncSetAttribute(reinterpret_cast<const void*>(&gemm128_kernel<0>),
                            hipFuncAttributeMaxDynamicSharedMemorySize, 131072);
  (void)hipFuncSetAttribute(reinterpret_cast<const void*>(&gemm128_kernel<1>),
                            hipFuncAttributeMaxDynamicSharedMemorySize, 131072);

  const int NX = B_ * T_ * C_;               // 8388608
  cvt_kernel<<<NX / (256 * 8), 256, 0, stream>>>(x, xb, NX);
  tconv_kernel<<<dim3(3 * C_ / 32, C_ / 32), dim3(32, 8), 0, stream>>>(wqkv, wqt, C_, 3 * C_);
  tconv_kernel<<<dim3(C_ / 32, C_ / 32), dim3(32, 8), 0, stream>>>(wo, wot, C_, C_);

  // QKV: M=8192/128=64 x N=3072/256=12 -> 768 blocks (3.0 rounds, 1 blk/CU)
  gemm128_kernel<0><<<768, 512, 131072, stream>>>(
      xb, wqt, bqkv, C_, 12, 3 * C_, qbuf, kbuf, vbuf, nullptr);

  vtr_kernel<<<dim3(B_ * H_, T_ / 64), 256, 0, stream>>>(vbuf, vtbuf);

  attn_kernel<<<dim3(B_ * H_, T_ / 64), 256, 0, stream>>>(qbuf, kbuf, vtbuf, ybuf);

  // out-proj: 64 x 4 -> 256 blocks (1.0 round)
  gemm128_kernel<1><<<256, 512, 131072, stream>>>(
      ybuf, wot, bo, C_, 4, C_, nullptr, nullptr, nullptr, out);
}

// Round 5
// 149.811 us; speedup vs baseline: 1.1161x; 1.0388x over previous
//
#include <hip/hip_runtime.h>
#include <cstddef>

// ---------------------------------------------------------------------------
// MHA block: y = attn(x@Wqkv+b) @ Wo + bo   (B=16,T=512,C=1024,H=16,hd=64)
// R5: QKV GEMM 256x192 (512 blocks = 2.0 even rounds, wave 128x48,
// all-reads-in-ph0 2-phase, counted vmcnt(4)). Out-proj/attn unchanged.
// ---------------------------------------------------------------------------

#define B_  16
#define T_  512
#define C_  1024
#define H_  16
#define HD_ 64

typedef __bf16 bf16x8 __attribute__((ext_vector_type(8)));
typedef float  f32x4  __attribute__((ext_vector_type(4)));

__device__ __forceinline__ void gload16(const void* g, void* lds_dst) {
  __builtin_amdgcn_global_load_lds(
      (const __attribute__((address_space(1))) unsigned int*)g,
      (__attribute__((address_space(3))) unsigned int*)lds_dst, 16, 0, 0);
}

// ------------------------- convert x: fp32 -> bf16 --------------------------
__global__ void cvt_kernel(const float* __restrict__ in, __bf16* __restrict__ out, int n) {
  int i = (blockIdx.x * 256 + threadIdx.x) * 8;
  if (i >= n) return;
  float4 f0 = *(const float4*)&in[i];
  float4 f1 = *(const float4*)&in[i + 4];
  bf16x8 o;
  o[0] = (__bf16)f0.x; o[1] = (__bf16)f0.y; o[2] = (__bf16)f0.z; o[3] = (__bf16)f0.w;
  o[4] = (__bf16)f1.x; o[5] = (__bf16)f1.y; o[6] = (__bf16)f1.z; o[7] = (__bf16)f1.w;
  *(bf16x8*)&out[i] = o;
}

// -------------- transpose+convert: w[K][N] fp32 -> wt[N][K] bf16 ------------
__global__ void tconv_kernel(const float* __restrict__ w, __bf16* __restrict__ wt,
                             int K, int N) {
  __shared__ float tile[32][33];
  int tx = threadIdx.x, ty = threadIdx.y;          // block (32,8)
  int n0 = blockIdx.x * 32, k0 = blockIdx.y * 32;
  #pragma unroll
  for (int i = 0; i < 4; ++i) {
    int r = ty + i * 8;
    tile[r][tx] = w[(size_t)(k0 + r) * N + n0 + tx];
  }
  __syncthreads();
  #pragma unroll
  for (int i = 0; i < 4; ++i) {
    int r = ty + i * 8;
    wt[(size_t)(n0 + r) * K + k0 + tx] = (__bf16)tile[tx][r];
  }
}

// ---------------- V transpose: v[bh][t][d] -> vt[bh][d][t] ------------------
__global__ void vtr_kernel(const __bf16* __restrict__ v, __bf16* __restrict__ vt) {
  __shared__ __bf16 tile[64][68];
  const int tid = threadIdx.x;
  const int bh = blockIdx.x, tc = blockIdx.y;      // 64-row t-chunk
  const size_t base = (size_t)bh * T_ * HD_;
  #pragma unroll
  for (int p = 0; p < 2; ++p) {
    int t8 = p * 256 + tid;
    int r = t8 >> 3, col = (t8 & 7) * 8;
    *(bf16x8*)&tile[r][col] =
        *(const bf16x8*)&v[base + (size_t)(tc * 64 + r) * HD_ + col];
  }
  __syncthreads();
  #pragma unroll
  for (int p = 0; p < 2; ++p) {
    int t8 = p * 256 + tid;
    int d = t8 >> 3, tt = (t8 & 7) * 8;
    bf16x8 o;
    #pragma unroll
    for (int i = 0; i < 8; ++i) o[i] = tile[tt + i][d];
    *(bf16x8*)&vt[base + (size_t)d * T_ + tc * 64 + tt] = o;
  }
}

// ---------------------------------------------------------------------------
// QKV GEMM: C[M][3C] = A[M][K] @ BT[3C][K]^T + bias, split to q/k/v [B,H,T,HD]
// Tile 256x192, BK=64, 8 waves (2M x 4N), per-wave 128x48 (8x3 16x16 frags).
// LDS 112KB: A dbuf 2x32KB @0, B dbuf 2x24KB @64KB. XOR swizzle on frag
// reads; staging pre-swizzles the GLOBAL source so gload_lds dest is linear.
// Per K-tile t (bufs p=t&1), 2 phases:
//   ph0: vmcnt(4)+bar; rdB(6)+rdA(16); stage B(t+1)->p^1; 24 MFMA mf0-3; bar
//   ph1: stage A(t+2)->p;                                 24 MFMA mf4-7; bar
// Hazards: stage A(t+2)->p after ALL p-reads (ph0) + barrier. stage B(t+1)
// ->p^1: readers were ph0(t-1), >=2 barriers prior. Outstanding entering
// ph0(t) = B(t)[3] + A(t+1)[4] -> wait B(t): vmcnt(4). Tail: vmcnt(0).
// ---------------------------------------------------------------------------
__global__ __launch_bounds__(512, 2) void gemm192_kernel(
    const __bf16* __restrict__ A, const __bf16* __restrict__ BT,
    const float* __restrict__ bias, int K, int NBn,
    __bf16* __restrict__ oq, __bf16* __restrict__ okk, __bf16* __restrict__ ov)
{
  extern __shared__ __align__(16) char lds[];
  const int tid = threadIdx.x, lane = tid & 63, wid = tid >> 6;
  const int wm = wid >> 2, wn = wid & 3;          // 2M x 4N
  const int lr = lane & 15, lg = lane >> 4;

  // bijective XCD swizzle (gridDim.x % 8 == 0)
  const int cpx = gridDim.x >> 3;
  const int id = (blockIdx.x & 7) * cpx + (blockIdx.x >> 3);
  const int m0 = (id / NBn) * 256, n0 = (id % NBn) * 192;

  // staging: one issue = 512 lanes x 16B = 8KB = 64 rows of 128B
  const int r8  = wid * 8 + (lane >> 3);
  const int csw = ((lane & 7) ^ (lane >> 3)) * 8;     // pre-swizzled col (elems)

  auto stageA = [&](const __bf16* g, char* dst) {     // 256x64 tile, 4 issues
    #pragma unroll
    for (int i = 0; i < 4; ++i)
      gload16(g + (size_t)(i * 64 + r8) * K + csw, dst + i * 8192 + wid * 1024);
  };
  auto stageB = [&](const __bf16* g, char* dst) {     // 192x64 tile, 3 issues
    #pragma unroll
    for (int i = 0; i < 3; ++i)
      gload16(g + (size_t)(i * 64 + r8) * K + csw, dst + i * 8192 + wid * 1024);
  };

  auto rdA = [&](bf16x8* d, const char* Ab) {         // 16 x ds_read_b128
    #pragma unroll
    for (int mf = 0; mf < 8; ++mf) {
      const char* rp = Ab + (wm * 128 + mf * 16 + lr) * 128;
      #pragma unroll
      for (int ks = 0; ks < 2; ++ks)
        d[mf * 2 + ks] = *(const bf16x8*)(rp + (((ks << 2) + lg) ^ (lr & 7)) * 16);
    }
  };
  auto rdB = [&](bf16x8* d, const char* Bb) {         // 6 x ds_read_b128
    #pragma unroll
    for (int nf = 0; nf < 3; ++nf) {
      const char* rp = Bb + (wn * 48 + nf * 16 + lr) * 128;
      #pragma unroll
      for (int ks = 0; ks < 2; ++ks)
        d[nf * 2 + ks] = *(const bf16x8*)(rp + (((ks << 2) + lg) ^ (lr & 7)) * 16);
    }
  };

  f32x4 acc[8][3] = {};

  auto mm = [&](int mh, const bf16x8* av, const bf16x8* bv) {   // 24 MFMA
    __builtin_amdgcn_s_setprio(1);
    #pragma unroll
    for (int mf = 0; mf < 4; ++mf)
      #pragma unroll
      for (int nf = 0; nf < 3; ++nf)
        #pragma unroll
        for (int ks = 0; ks < 2; ++ks)
          acc[mh * 4 + mf][nf] = __builtin_amdgcn_mfma_f32_16x16x32_bf16(
              av[(mh * 4 + mf) * 2 + ks], bv[nf * 2 + ks], acc[mh * 4 + mf][nf],
              0, 0, 0);
    __builtin_amdgcn_s_setprio(0);
  };

  const int nt = K >> 6;                              // 16
  const __bf16* gA = A  + (size_t)m0 * K;
  const __bf16* gB = BT + (size_t)n0 * K;
  char* const Ab0 = lds;                              // 2 x 32KB
  char* const Bb0 = lds + 65536;                      // 2 x 24KB

  // prologue: A(0), B(0), A(1)  -> 11 outstanding
  stageA(gA, Ab0);
  stageB(gB, Bb0);
  stageA(gA + 64, Ab0 + 32768);

  bf16x8 a[16], b[6];

  for (int t = 0; t < nt; ++t) {
    const int p = t & 1;
    char* Ab = Ab0 + p * 32768;
    char* Bb = Bb0 + p * 24576;
    char* Bn = Bb0 + (p ^ 1) * 24576;

    // ---- ph0 ----
    if (t + 1 < nt) { asm volatile("s_waitcnt vmcnt(4)\ns_barrier" ::: "memory"); }
    else            { asm volatile("s_waitcnt vmcnt(0)\ns_barrier" ::: "memory"); }
    rdB(b, Bb);
    rdA(a, Ab);
    if (t + 1 < nt) stageB(gB + (size_t)(t + 1) * 64, Bn);
    mm(0, a, b);
    asm volatile("s_barrier" ::: "memory");

    // ---- ph1 ----
    if (t + 2 < nt) stageA(gA + (size_t)(t + 2) * 64, Ab);
    mm(1, a, b);
    asm volatile("s_barrier" ::: "memory");
  }

  // ---- epilogue: split q/k/v; D row = lg*4+j, col = lr per 16x16 frag ----
  #pragma unroll
  for (int nf = 0; nf < 3; ++nf) {
    int n = n0 + wn * 48 + nf * 16 + lr;
    float bv = bias[n];
    int which = n >> 10;
    __bf16* dst = (which == 0) ? oq : (which == 1) ? okk : ov;
    int h = (n >> 6) & 15, d = n & 63;
    #pragma unroll
    for (int mf = 0; mf < 8; ++mf)
      #pragma unroll
      for (int j = 0; j < 4; ++j) {
        int m = m0 + wm * 128 + mf * 16 + lg * 4 + j;
        int bb = m >> 9, tt = m & 511;
        dst[(size_t)((bb * H_ + h) * T_ + tt) * HD_ + d] =
            (__bf16)(acc[mf][nf][j] + bv);
      }
  }
}

// ---------------------------------------------------------------------------
// Out-proj GEMM (R4 structure, verified): C[M][N] = A@BT^T + bias, fp32 out.
// Tile 128x256, BK=64, 8 waves (2M x 4N), per-wave 64x64.
// ---------------------------------------------------------------------------
__global__ __launch_bounds__(512, 2) void gemm128_kernel(
    const __bf16* __restrict__ A, const __bf16* __restrict__ BT,
    const float* __restrict__ bias, int K, int NBn, int N,
    float* __restrict__ out32)
{
  extern __shared__ __align__(16) char lds[];
  const int tid = threadIdx.x, lane = tid & 63, wid = tid >> 6;
  const int wm = wid >> 2, wn = wid & 3;          // 2M x 4N
  const int lr = lane & 15, lg = lane >> 4;

  const int cpx = gridDim.x >> 3;
  const int id = (blockIdx.x & 7) * cpx + (blockIdx.x >> 3);
  const int m0 = (id / NBn) * 128, n0 = (id % NBn) * 256;

  const int r8  = wid * 8 + (lane >> 3);
  const int csw = ((lane & 7) ^ (lane >> 3)) * 8;

  auto stageA = [&](const __bf16* g, char* dst) {     // 128x64, 2 issues
    #pragma unroll
    for (int i = 0; i < 2; ++i)
      gload16(g + (size_t)(i * 64 + r8) * K + csw, dst + i * 8192 + wid * 1024);
  };
  auto stageB = [&](const __bf16* g, char* dst) {     // 256x64, 4 issues
    #pragma unroll
    for (int i = 0; i < 4; ++i)
      gload16(g + (size_t)(i * 64 + r8) * K + csw, dst + i * 8192 + wid * 1024);
  };

  auto rdA = [&](bf16x8* d, const char* Ab) {
    #pragma unroll
    for (int mf = 0; mf < 4; ++mf) {
      const char* rp = Ab + (wm * 64 + mf * 16 + lr) * 128;
      #pragma unroll
      for (int ks = 0; ks < 2; ++ks)
        d[mf * 2 + ks] = *(const bf16x8*)(rp + (((ks << 2) + lg) ^ (lr & 7)) * 16);
    }
  };
  auto rdB = [&](bf16x8* d, const char* Bb, int nh) {
    #pragma unroll
    for (int nfl = 0; nfl < 2; ++nfl) {
      const char* rp = Bb + (wn * 64 + (nh * 2 + nfl) * 16 + lr) * 128;
      #pragma unroll
      for (int ks = 0; ks < 2; ++ks)
        d[nfl * 2 + ks] = *(const bf16x8*)(rp + (((ks << 2) + lg) ^ (lr & 7)) * 16);
    }
  };

  f32x4 acc[4][4] = {};

  auto mm = [&](const bf16x8* av, const bf16x8* bv, int nh) {
    __builtin_amdgcn_s_setprio(1);
    #pragma unroll
    for (int mf = 0; mf < 4; ++mf)
      #pragma unroll
      for (int nfl = 0; nfl < 2; ++nfl)
        #pragma unroll
        for (int ks = 0; ks < 2; ++ks)
          acc[mf][nh * 2 + nfl] = __builtin_amdgcn_mfma_f32_16x16x32_bf16(
              av[mf * 2 + ks], bv[nfl * 2 + ks], acc[mf][nh * 2 + nfl], 0, 0, 0);
    __builtin_amdgcn_s_setprio(0);
  };

  const int nt = K >> 6;
  const __bf16* gA = A  + (size_t)m0 * K;
  const __bf16* gB = BT + (size_t)n0 * K;
  char* const Ab0 = lds;
  char* const Bb0 = lds + 32768;

  stageB(gB, Bb0);
  stageA(gA, Ab0);
  stageB(gB + 64, Bb0 + 32768);
  stageA(gA + 64, Ab0 + 16384);

  bf16x8 a[8], b0[4], b1[4];

  for (int t = 0; t < nt; ++t) {
    char* Ab = Ab0 + (t & 1) * 16384;
    char* Bb = Bb0 + (t % 3) * 32768;

    if (t + 1 < nt) { asm volatile("s_waitcnt vmcnt(6)\ns_barrier" ::: "memory"); }
    else            { asm volatile("s_waitcnt vmcnt(0)\ns_barrier" ::: "memory"); }
    rdA(a, Ab);
    rdB(b0, Bb, 0);
    if (t + 2 < nt) stageB(gB + (size_t)(t + 2) * 64, Bb0 + ((t + 2) % 3) * 32768);
    mm(a, b0, 0);
    asm volatile("s_barrier" ::: "memory");

    rdB(b1, Bb, 1);
    if (t + 2 < nt) stageA(gA + (size_t)(t + 2) * 64, Ab);
    mm(a, b1, 1);
    asm volatile("s_barrier" ::: "memory");
  }

  #pragma unroll
  for (int nf = 0; nf < 4; ++nf) {
    int n = n0 + wn * 64 + nf * 16 + lr;
    float bv = bias[n];
    #pragma unroll
    for (int mf = 0; mf < 4; ++mf)
      #pragma unroll
      for (int j = 0; j < 4; ++j) {
        int m = m0 + wm * 64 + mf * 16 + lg * 4 + j;
        out32[(size_t)m * N + n] = acc[mf][nf][j] + bv;
      }
  }
}

// ---------------------------------------------------------------------------
// Flash attention (causal). Grid (B*H, T/64). 4 waves, each wave 16 q-rows.
// V pre-transposed: vt[bh][d][t] -> Vt staging is coalesced b128, no scatter.
// ---------------------------------------------------------------------------
__global__ __launch_bounds__(256, 2) void attn_kernel(
    const __bf16* __restrict__ qb, const __bf16* __restrict__ kb,
    const __bf16* __restrict__ vtb, __bf16* __restrict__ y)
{
  __shared__ __attribute__((aligned(16))) __bf16 Ks[64][72];
  __shared__ __attribute__((aligned(16))) __bf16 Vt[64][72];
  __shared__ __attribute__((aligned(16))) __bf16 Ps[4][16][72];

  const int tid = threadIdx.x, lane = tid & 63, w = tid >> 6;
  const int lr = lane & 15, lg = lane >> 4;
  const int bh = blockIdx.x, qt = blockIdx.y;
  const size_t base = (size_t)bh * T_ * HD_;
  const int q0 = qt * 64 + w * 16;
  const float SCALE = 0.03125f;                   // 1/sqrt(1024)
  const float L2E = 1.44269504088896f;

  const int r_  = tid >> 3;                       // 0..31 (+32 for p=1)
  const int c8_ = (tid & 7) * 8;

  bf16x8 qf[2];
  #pragma unroll
  for (int s = 0; s < 2; ++s)
    qf[s] = *(const bf16x8*)&qb[base + (size_t)(q0 + lr) * HD_ + s * 32 + lg * 8];

  f32x4 acc[4] = {};
  float mrun[4] = { -__builtin_inff(), -__builtin_inff(),
                    -__builtin_inff(), -__builtin_inff() };
  float lrun[4] = { 0.f, 0.f, 0.f, 0.f };

  bf16x8 kk[2], vv[2], kk2[2], vv2[2];
  #pragma unroll
  for (int p = 0; p < 2; ++p) {
    int rr = p * 32 + r_;
    kk[p] = *(const bf16x8*)&kb[base + (size_t)rr * HD_ + c8_];
    vv[p] = *(const bf16x8*)&vtb[base + (size_t)rr * T_ + c8_];
  }

  for (int c = 0; c <= qt; ++c) {
    #pragma unroll
    for (int p = 0; p < 2; ++p) {
      int rr = p * 32 + r_;
      *(bf16x8*)&Ks[rr][c8_] = kk[p];
      *(bf16x8*)&Vt[rr][c8_] = vv[p];
    }
    __syncthreads();

    if (c < qt) {
      #pragma unroll
      for (int p = 0; p < 2; ++p) {
        int rr = p * 32 + r_;
        kk2[p] = *(const bf16x8*)&kb[base + (size_t)(c + 1) * 64 * HD_ + (size_t)rr * HD_ + c8_];
        vv2[p] = *(const bf16x8*)&vtb[base + (size_t)rr * T_ + (c + 1) * 64 + c8_];
      }
    }

    f32x4 sc[4] = {};
    #pragma unroll
    for (int s = 0; s < 2; ++s) {
      #pragma unroll
      for (int cc = 0; cc < 4; ++cc) {
        bf16x8 kf = *(const bf16x8*)&Ks[cc * 16 + lr][s * 32 + lg * 8];
        sc[cc] = __builtin_amdgcn_mfma_f32_16x16x32_bf16(qf[s], kf, sc[cc], 0, 0, 0);
      }
    }

    #pragma unroll
    for (int cc = 0; cc < 4; ++cc)
      #pragma unroll
      for (int j = 0; j < 4; ++j) {
        float v = sc[cc][j] * SCALE;
        if (c == qt) {
          int kv = c * 64 + cc * 16 + lr;
          int qr = q0 + lg * 4 + j;
          if (kv > qr) v = -__builtin_inff();
        }
        sc[cc][j] = v;
      }

    float mx[4];
    #pragma unroll
    for (int j = 0; j < 4; ++j)
      mx[j] = fmaxf(fmaxf(sc[0][j], sc[1][j]), fmaxf(sc[2][j], sc[3][j]));
    #pragma unroll
    for (int msk = 1; msk <= 8; msk <<= 1)
      #pragma unroll
      for (int j = 0; j < 4; ++j)
        mx[j] = fmaxf(mx[j], __shfl_xor(mx[j], msk, 64));
    float corr[4];
    #pragma unroll
    for (int j = 0; j < 4; ++j) {
      float nm = fmaxf(mrun[j], mx[j]);
      corr[j] = exp2f((mrun[j] - nm) * L2E);
      mrun[j] = nm;
    }
    #pragma unroll
    for (int cc = 0; cc < 4; ++cc)
      #pragma unroll
      for (int j = 0; j < 4; ++j)
        sc[cc][j] = exp2f((sc[cc][j] - mrun[j]) * L2E);
    float rs[4];
    #pragma unroll
    for (int j = 0; j < 4; ++j)
      rs[j] = sc[0][j] + sc[1][j] + sc[2][j] + sc[3][j];
    #pragma unroll
    for (int msk = 1; msk <= 8; msk <<= 1)
      #pragma unroll
      for (int j = 0; j < 4; ++j)
        rs[j] += __shfl_xor(rs[j], msk, 64);
    #pragma unroll
    for (int j = 0; j < 4; ++j)
      lrun[j] = lrun[j] * corr[j] + rs[j];
    #pragma unroll
    for (int dd = 0; dd < 4; ++dd)
      #pragma unroll
      for (int j = 0; j < 4; ++j)
        acc[dd][j] *= corr[j];

    #pragma unroll
    for (int cc = 0; cc < 4; ++cc)
      #pragma unroll
      for (int j = 0; j < 4; ++j)
        Ps[w][lg * 4 + j][cc * 16 + lr] = (__bf16)sc[cc][j];

    #pragma unroll
    for (int s = 0; s < 2; ++s) {
      bf16x8 pa = *(const bf16x8*)&Ps[w][lr][s * 32 + lg * 8];
      #pragma unroll
      for (int dd = 0; dd < 4; ++dd) {
        bf16x8 vf = *(const bf16x8*)&Vt[dd * 16 + lr][s * 32 + lg * 8];
        acc[dd] = __builtin_amdgcn_mfma_f32_16x16x32_bf16(pa, vf, acc[dd], 0, 0, 0);
      }
    }
    __syncthreads();
    #pragma unroll
    for (int p = 0; p < 2; ++p) { kk[p] = kk2[p]; vv[p] = vv2[p]; }
  }

  const int b = bh >> 4, h = bh & 15;
  #pragma unroll
  for (int dd = 0; dd < 4; ++dd)
    #pragma unroll
    for (int j = 0; j < 4; ++j) {
      int t = q0 + lg * 4 + j;
      int d = dd * 16 + lr;
      y[((size_t)(b * T_ + t)) * C_ + h * HD_ + d] = (__bf16)(acc[dd][j] / lrun[j]);
    }
}

// ---------------------------------------------------------------------------
extern "C" void kernel_launch(void* const* d_in, const int* in_sizes, int n_in,
                              void* d_out, int out_size, void* d_ws, size_t ws_size,
                              hipStream_t stream) {
  const float* x    = (const float*)d_in[0];
  const float* wqkv = (const float*)d_in[1];
  const float* bqkv = (const float*)d_in[2];
  const float* wo   = (const float*)d_in[3];
  const float* bo   = (const float*)d_in[4];
  float* out = (float*)d_out;

  char* ws = (char*)d_ws;
  const size_t MB = 1u << 20;
  __bf16* xb    = (__bf16*)(ws);              // 16 MB  x bf16 [8192][1024]
  __bf16* wqt   = (__bf16*)(ws + 16 * MB);    //  6 MB  w_qkv^T bf16 [3072][1024]
  __bf16* wot   = (__bf16*)(ws + 22 * MB);    //  2 MB  w_o^T bf16 [1024][1024]
  __bf16* qbuf  = (__bf16*)(ws + 24 * MB);    // 16 MB  Q [B,H,T,HD]
  __bf16* kbuf  = (__bf16*)(ws + 40 * MB);    // 16 MB  K [B,H,T,HD]
  __bf16* vbuf  = (__bf16*)(ws + 56 * MB);    // 16 MB  V [B,H,T,HD]
  __bf16* ybuf  = (__bf16*)(ws + 56 * MB);    // aliases vbuf (dead after vtr)
  __bf16* vtbuf = (__bf16*)(ws + 72 * MB);    // 16 MB  V^T [B,H,HD,T]

  (void)hipFuncSetAttribute(reinterpret_cast<const void*>(&gemm192_kernel),
                            hipFuncAttributeMaxDynamicSharedMemorySize, 114688);
  (void)hipFuncSetAttribute(reinterpret_cast<const void*>(&gemm128_kernel),
                            hipFuncAttributeMaxDynamicSharedMemorySize, 131072);

  const int NX = B_ * T_ * C_;               // 8388608
  cvt_kernel<<<NX / (256 * 8), 256, 0, stream>>>(x, xb, NX);
  tconv_kernel<<<dim3(3 * C_ / 32, C_ / 32), dim3(32, 8), 0, stream>>>(wqkv, wqt, C_, 3 * C_);
  tconv_kernel<<<dim3(C_ / 32, C_ / 32), dim3(32, 8), 0, stream>>>(wo, wot, C_, C_);

  // QKV: 8192/256=32 x 3072/192=16 -> 512 blocks (2.0 rounds, 1 blk/CU)
  gemm192_kernel<<<512, 512, 114688, stream>>>(
      xb, wqt, bqkv, C_, 16, qbuf, kbuf, vbuf);

  vtr_kernel<<<dim3(B_ * H_, T_ / 64), 256, 0, stream>>>(vbuf, vtbuf);

  attn_kernel<<<dim3(B_ * H_, T_ / 64), 256, 0, stream>>>(qbuf, kbuf, vtbuf, ybuf);

  // out-proj: 64 x 4 -> 256 blocks (1.0 round)
  gemm128_kernel<<<256, 512, 131072, stream>>>(
      ybuf, wot, bo, C_, 4, C_, out);
}